// Round 4
// baseline (513.290 us; speedup 1.0000x reference)
//
#include <hip/hip_runtime.h>
#include <math.h>

#define KCODES 1024
#define DDIM   256
#define HWSZ   1024
#define CHW    262144
#define LOSS_OFF 16777216
#define IDX_OFF  16777217

// scratch carved out of d_out's out-region (epilogue overwrites it at the end)
#define EH_OFF   1000000   // 262144 bf16 (131072 f32 slots)
#define EL_OFF   1200000
#define AN_OFF   1400000   // 65536 f32
#define BN_OFF   1500000   // 1024 f32
#define LIST_OFF 1550000   // up to 65536 int
#define CNT_OFF  1650000   // 1 int
#define TAU_GAP  1e-4f

typedef __attribute__((ext_vector_type(8))) short short8v;
typedef __attribute__((ext_vector_type(4))) float float4v;

static __device__ __forceinline__ unsigned short bf16_rne(float f) {
    unsigned u = __float_as_uint(f);
    return (unsigned short)((u + 0x7FFFu + ((u >> 16) & 1u)) >> 16);
}
static __device__ __forceinline__ float bf16_tf(unsigned short h) {
    return __uint_as_float(((unsigned)h) << 16);
}

// ---- prep: Bn (ref pairwise order), eh/el fragment scatter, zero count/loss
__global__ __launch_bounds__(256) void vq_prep_e(const float* __restrict__ emb,
                                                 float* __restrict__ outp) {
    int k = blockIdx.x * 256 + threadIdx.x;
    if (k >= KCODES) return;
    if (k == 0) { *(int*)(outp + CNT_OFF) = 0; outp[LOSS_OFF] = 0.f; }
    const float* e = emb + (size_t)k * DDIM;
    // Bn with numpy-pairwise summation order (proven in round 3)
    {
        float half[2];
        #pragma unroll
        for (int h = 0; h < 2; ++h) {
            const float* q = e + (h << 7);
            float r[8];
            #pragma unroll
            for (int j = 0; j < 8; ++j) r[j] = __fmul_rn(q[j], q[j]);
            for (int i = 8; i < 128; i += 8) {
                #pragma unroll
                for (int j = 0; j < 8; ++j)
                    r[j] = __fadd_rn(r[j], __fmul_rn(q[i + j], q[i + j]));
            }
            half[h] = __fadd_rn(
                __fadd_rn(__fadd_rn(r[0], r[1]), __fadd_rn(r[2], r[3])),
                __fadd_rn(__fadd_rn(r[4], r[5]), __fadd_rn(r[6], r[7])));
        }
        outp[BN_OFF + k] = __fadd_rn(half[0], half[1]);
    }
    // eh/el scattered into MFMA A-fragment order:
    // [kw16 = k>>4][s32 = d>>5][ (m + 16*g)*8 + j ], m=k&15, g=(d>>3)&3, j=d&7
    unsigned short* EH = (unsigned short*)(outp + EH_OFF);
    unsigned short* EL = (unsigned short*)(outp + EL_OFF);
    const int kw = k >> 4, m = k & 15;
    for (int d = 0; d < DDIM; ++d) {
        float f = e[d];
        unsigned short hb = bf16_rne(f);
        unsigned short lb = bf16_rne(f - bf16_tf(hb));
        int flat = kw * 4096 + (d >> 5) * 512 + ((m + 16 * ((d >> 3) & 3)) << 3) + (d & 7);
        EH[flat] = hb; EL[flat] = lb;
    }
}

// ---- An = ||z_n||^2, numpy-pairwise order (proven in round 3) -------------
__global__ __launch_bounds__(256) void vq_znorm(const float* __restrict__ z,
                                                float* __restrict__ outp) {
    const int blk = blockIdx.x;
    const int b   = blk >> 2;
    const int hw  = ((blk & 3) << 8) + threadIdx.x;
    const float* p = z + (size_t)b * CHW + hw;
    float half[2];
    #pragma unroll
    for (int h = 0; h < 2; ++h) {
        const float* q = p + (size_t)(h << 7) * HWSZ;
        float r[8];
        #pragma unroll
        for (int j = 0; j < 8; ++j) {
            float v = q[(size_t)j * HWSZ];
            r[j] = __fmul_rn(v, v);
        }
        for (int i = 8; i < 128; i += 8) {
            #pragma unroll
            for (int j = 0; j < 8; ++j) {
                float v = q[(size_t)(i + j) * HWSZ];
                r[j] = __fadd_rn(r[j], __fmul_rn(v, v));
            }
        }
        half[h] = __fadd_rn(
            __fadd_rn(__fadd_rn(r[0], r[1]), __fadd_rn(r[2], r[3])),
            __fadd_rn(__fadd_rn(r[4], r[5]), __fadd_rn(r[6], r[7])));
    }
    outp[AN_OFF + ((size_t)b << 10) + hw] = __fadd_rn(half[0], half[1]);
}

// ---- main: split-bf16 MFMA distance GEMM + top-2 argmin -------------------
// 512 blocks x 512 threads (8 waves). Block: 128 pixels, full K=1024.
// kt loop (4 x 256 codes); dh (2 x 128 d, z staged hi/lo in LDS per half);
// dc (4 x 32 d, E chunk staged). Wave tile 64k x 64n (4x4 16x16x32 frags).
__global__ __launch_bounds__(512, 2) void vq_argmin_mfma(
        const float* __restrict__ z, float* __restrict__ outp) {
    __shared__ unsigned short ZH[16384];   // [nwl 0..7][s32loc 0..3][512]
    __shared__ unsigned short ZL[16384];
    __shared__ unsigned short EH[8192];    // [kwl 0..15][512]
    __shared__ unsigned short EL[8192];
    __shared__ float BNs[1024];
    __shared__ float REDv[2][64][16];
    __shared__ int   REDi[2][64][16];
    __shared__ float REDw[2][64][16];

    const int t = threadIdx.x;
    const int bid = blockIdx.x;
    const int nb = ((bid & 7) << 6) + (bid >> 3);   // bijective XCD swizzle (512%8==0)
    const int b   = nb >> 3;
    const int hw0 = (nb & 7) << 7;

    const int lane = t & 63;
    const int w    = t >> 6;
    const int kwv  = w >> 1;     // 0..3  k-group
    const int nwv  = w & 1;      // 0..1  n-group
    const int l8   = lane << 3;
    const int g2   = lane >> 4;

    // stage Bn to LDS (read-only afterwards)
    BNs[t] = outp[BN_OFF + t];
    BNs[t + 512] = outp[BN_OFF + t + 512];

    float an[4];
    #pragma unroll
    for (int nf = 0; nf < 4; ++nf)
        an[nf] = outp[AN_OFF + ((size_t)b << 10) + hw0 + nwv * 64 + nf * 16 + (lane & 15)];

    float mv1[4], mv2[4]; int mi1[4];
    #pragma unroll
    for (int i = 0; i < 4; ++i) { mv1[i] = 3.4e38f; mv2[i] = 3.4e38f; mi1[i] = 0x7fffffff; }

    const uint4* ehw = (const uint4*)(outp + EH_OFF);
    const uint4* elw = (const uint4*)(outp + EL_OFF);

    for (int kt = 0; kt < 4; ++kt) {
        float4v acc[4][4];
        #pragma unroll
        for (int a = 0; a < 4; ++a)
            #pragma unroll
            for (int c = 0; c < 4; ++c) acc[a][c] = (float4v){0.f, 0.f, 0.f, 0.f};

        for (int dh = 0; dh < 2; ++dh) {
            const int d0 = dh << 7;
            __syncthreads();  // previous readers of Z/E done
            // stage Z half: f32 -> (hi,lo) bf16, B-fragment order
            {
                const int n4 = (t & 31) << 2;
                const int dbase = t >> 5;
                #pragma unroll
                for (int it = 0; it < 8; ++it) {
                    int dd = dbase + it * 16;   // 0..127
                    const float4 v = *(const float4*)(z + (size_t)b * CHW
                                        + (size_t)(d0 + dd) * HWSZ + hw0 + n4);
                    int sl = dd >> 5, g = (dd >> 3) & 3, j = dd & 7;
                    float fv[4] = {v.x, v.y, v.z, v.w};
                    #pragma unroll
                    for (int nn = 0; nn < 4; ++nn) {
                        int n = n4 + nn;
                        unsigned short hb = bf16_rne(fv[nn]);
                        unsigned short lb = bf16_rne(fv[nn] - bf16_tf(hb));
                        int flat = ((n >> 4) << 11) + (sl << 9) + (((n & 15) + (g << 4)) << 3) + j;
                        ZH[flat] = hb; ZL[flat] = lb;
                    }
                }
            }
            for (int dc = 0; dc < 4; ++dc) {
                const int s32g = (dh << 2) + dc;
                if (dc > 0) __syncthreads();   // readers of previous E chunk done
                #pragma unroll
                for (int p = 0; p < 4; ++p) {  // stage E chunk: 2048 uint4 = 32KB
                    int s = t + p * 512;
                    int hl = s >> 10, ss = s & 1023;
                    int kwl = ss >> 6, ww = ss & 63;
                    const uint4* src = (hl ? elw : ehw)
                          + (size_t)(kt * 16 + kwl) * 512 + s32g * 64 + ww;
                    *(((uint4*)(hl ? EL : EH)) + ss) = *src;
                }
                __syncthreads();
                short8v ah[4], al[4], bh[4], bl[4];
                #pragma unroll
                for (int kf = 0; kf < 4; ++kf) {
                    int base = ((kwv * 4 + kf) << 9) + l8;
                    ah[kf] = *(const short8v*)&EH[base];
                    al[kf] = *(const short8v*)&EL[base];
                }
                #pragma unroll
                for (int nf = 0; nf < 4; ++nf) {
                    int base = ((nwv * 4 + nf) << 11) + (dc << 9) + l8;
                    bh[nf] = *(const short8v*)&ZH[base];
                    bl[nf] = *(const short8v*)&ZL[base];
                }
                #pragma unroll
                for (int kf = 0; kf < 4; ++kf)
                    #pragma unroll
                    for (int nf = 0; nf < 4; ++nf) {
                        acc[kf][nf] = __builtin_amdgcn_mfma_f32_16x16x32_bf16(ah[kf], bh[nf], acc[kf][nf], 0, 0, 0);
                        acc[kf][nf] = __builtin_amdgcn_mfma_f32_16x16x32_bf16(ah[kf], bl[nf], acc[kf][nf], 0, 0, 0);
                        acc[kf][nf] = __builtin_amdgcn_mfma_f32_16x16x32_bf16(al[kf], bh[nf], acc[kf][nf], 0, 0, 0);
                    }
            }
        }
        // fold: s = fl(fl(A+B) - fl(2*dot)), first-index ties
        #pragma unroll
        for (int kf = 0; kf < 4; ++kf)
            #pragma unroll
            for (int nf = 0; nf < 4; ++nf)
                #pragma unroll
                for (int r = 0; r < 4; ++r) {
                    int k = kt * 256 + kwv * 64 + kf * 16 + g2 * 4 + r;
                    float s = __fsub_rn(__fadd_rn(an[nf], BNs[k]),
                                        __fmul_rn(2.0f, acc[kf][nf][r]));
                    if (s < mv1[nf] || (s == mv1[nf] && k < mi1[nf])) {
                        mv2[nf] = fminf(mv2[nf], mv1[nf]);
                        mv1[nf] = s; mi1[nf] = k;
                    } else if (s < mv2[nf]) mv2[nf] = s;
                }
    }

    #pragma unroll
    for (int nf = 0; nf < 4; ++nf) {
        int nl = nf * 16 + (lane & 15);
        int slot = kwv * 4 + g2;
        REDv[nwv][nl][slot] = mv1[nf];
        REDi[nwv][nl][slot] = mi1[nf];
        REDw[nwv][nl][slot] = mv2[nf];
    }
    __syncthreads();
    if (t < 128) {
        int nv = t >> 6, nl = t & 63;
        float bv = 3.4e38f, b2 = 3.4e38f; int bi = 0x7fffffff;
        #pragma unroll
        for (int s = 0; s < 16; ++s) {
            float v1 = REDv[nv][nl][s], v2 = REDw[nv][nl][s];
            int   i1 = REDi[nv][nl][s];
            if (v1 < bv || (v1 == bv && i1 < bi)) {
                b2 = fminf(b2, bv); bv = v1; bi = i1;
            } else b2 = fminf(b2, v1);
            b2 = fminf(b2, v2);
        }
        int n_glob = b * 1024 + hw0 + nv * 64 + nl;
        outp[IDX_OFF + n_glob] = (float)bi;
        if (b2 - bv < TAU_GAP) {
            int pos = atomicAdd((int*)(outp + CNT_OFF), 1);
            ((int*)(outp + LIST_OFF))[pos] = n_glob;
        }
    }
}

// ---- exact (f64-dot) rescore of near-tied rows, ref-bucketed scoring ------
__global__ __launch_bounds__(256) void vq_rescore(const float* __restrict__ z,
                                                  const float* __restrict__ emb,
                                                  float* __restrict__ outp) {
    const int cnt = *(const int*)(outp + CNT_OFF);
    const int t = threadIdx.x;
    __shared__ float zs[256];
    __shared__ float sv[256];
    __shared__ int   si[256];
    for (int i = blockIdx.x; i < cnt; i += gridDim.x) {
        int n = ((const int*)(outp + LIST_OFF))[i];
        int b = n >> 10, hw = n & 1023;
        __syncthreads();
        zs[t] = z[(size_t)b * CHW + (size_t)t * HWSZ + hw];
        __syncthreads();
        float An = outp[AN_OFF + n];
        float bestv = 3.4e38f; int besti = 0x7fffffff;
        #pragma unroll
        for (int kb = 0; kb < 4; ++kb) {
            int k = kb * 256 + t;
            const float4* e4 = (const float4*)(emb + (size_t)k * DDIM);
            double dot = 0.0;
            for (int q = 0; q < 64; ++q) {
                float4 v = e4[q];
                const float* zq = &zs[q << 2];
                dot += (double)v.x * zq[0] + (double)v.y * zq[1]
                     + (double)v.z * zq[2] + (double)v.w * zq[3];
            }
            float s = __fsub_rn(__fadd_rn(An, outp[BN_OFF + k]),
                                __fmul_rn(2.0f, (float)dot));
            if (s < bestv || (s == bestv && k < besti)) { bestv = s; besti = k; }
        }
        sv[t] = bestv; si[t] = besti;
        __syncthreads();
        for (int st = 128; st > 0; st >>= 1) {
            if (t < st) {
                float ov = sv[t + st]; int oi = si[t + st];
                if (ov < sv[t] || (ov == sv[t] && oi < si[t])) { sv[t] = ov; si[t] = oi; }
            }
            __syncthreads();
        }
        if (t == 0) outp[IDX_OFF + n] = (float)si[0];
    }
}

// ---- gather codebook rows, write out, loss (proven in round 3) ------------
__global__ __launch_bounds__(256) void vq_epilogue(const float* __restrict__ z,
                                                   const float* __restrict__ emb,
                                                   float* __restrict__ outp,
                                                   const float* __restrict__ idxf,
                                                   float* __restrict__ loss_slot) {
    const int t  = threadIdx.x;
    const int nc = blockIdx.x;
    const int b  = nc >> 4;
    const int hw = ((nc & 15) << 6) + (t & 63);
    const int n  = (b << 10) + hw;
    const int idx = (int)idxf[n];
    const float* erow = emb + (size_t)idx * DDIM;
    const size_t zb = (size_t)b * CHW + hw;

    float accl = 0.f;
    const int cbase = (t >> 6) << 2;
    #pragma unroll 4
    for (int cq = 0; cq < 16; ++cq) {
        int c = cbase + (cq << 4);
        float4 q4 = *reinterpret_cast<const float4*>(erow + c);
        float qv[4] = {q4.x, q4.y, q4.z, q4.w};
        #pragma unroll
        for (int j = 0; j < 4; ++j) {
            size_t a = zb + (size_t)(c + j) * HWSZ;
            float zv = z[a];
            outp[a] = qv[j];
            float d = qv[j] - zv;
            accl = fmaf(d, d, accl);
        }
    }
    #pragma unroll
    for (int off = 32; off > 0; off >>= 1)
        accl += __shfl_down(accl, off, 64);
    __shared__ float r[4];
    if ((t & 63) == 0) r[t >> 6] = accl;
    __syncthreads();
    if (t == 0) {
        float s = (r[0] + r[1]) + (r[2] + r[3]);
        atomicAdd(loss_slot, s * (1.25f / 16777216.f));
    }
}

extern "C" void kernel_launch(void* const* d_in, const int* in_sizes, int n_in,
                              void* d_out, int out_size, void* d_ws, size_t ws_size,
                              hipStream_t stream) {
    const float* z   = (const float*)d_in[0];
    const float* emb = (const float*)d_in[1];
    float* out       = (float*)d_out;

    vq_prep_e     <<<dim3(4),    dim3(256), 0, stream>>>(emb, out);
    vq_znorm      <<<dim3(256),  dim3(256), 0, stream>>>(z, out);
    vq_argmin_mfma<<<dim3(512),  dim3(512), 0, stream>>>(z, out);
    vq_rescore    <<<dim3(256),  dim3(256), 0, stream>>>(z, emb, out);
    vq_epilogue   <<<dim3(1024), dim3(256), 0, stream>>>(z, emb, out,
                                                         out + IDX_OFF, out + LOSS_OFF);
}

// Round 5
// 388.803 us; speedup vs baseline: 1.3202x; 1.3202x over previous
//
#include <hip/hip_runtime.h>
#include <math.h>

#define KCODES 1024
#define DDIM   256
#define HWSZ   1024
#define CHW    262144
#define LOSS_OFF 16777216
#define IDX_OFF  16777217

// scratch carved out of d_out's out-region (epilogue overwrites it at the end)
#define EH_OFF   1000000   // 262144 bf16 (131072 f32 slots)
#define EL_OFF   1200000
#define AN_OFF   1400000   // 65536 f32
#define BN_OFF   1500000   // 1024 f32
#define LIST_OFF 1550000   // up to 65536 int
#define CNT_OFF  1650000   // 1 int
#define TAU_GAP  1e-4f

typedef __attribute__((ext_vector_type(8))) short short8v;
typedef __attribute__((ext_vector_type(4))) float float4v;

static __device__ __forceinline__ unsigned short bf16_rne(float f) {
    unsigned u = __float_as_uint(f);
    return (unsigned short)((u + 0x7FFFu + ((u >> 16) & 1u)) >> 16);
}
static __device__ __forceinline__ float bf16_tf(unsigned short h) {
    return __uint_as_float(((unsigned)h) << 16);
}

// ---- prep 1: Bn (ref pairwise order) + zero count/loss --------------------
__global__ __launch_bounds__(256) void vq_prep_bn(const float* __restrict__ emb,
                                                  float* __restrict__ outp) {
    int k = blockIdx.x * 256 + threadIdx.x;
    if (k >= KCODES) return;
    if (k == 0) { *(int*)(outp + CNT_OFF) = 0; outp[LOSS_OFF] = 0.f; }
    const float* e = emb + (size_t)k * DDIM;
    float half[2];
    #pragma unroll
    for (int h = 0; h < 2; ++h) {
        const float* q = e + (h << 7);
        float r[8];
        #pragma unroll
        for (int j = 0; j < 8; ++j) r[j] = __fmul_rn(q[j], q[j]);
        for (int i = 8; i < 128; i += 8) {
            #pragma unroll
            for (int j = 0; j < 8; ++j)
                r[j] = __fadd_rn(r[j], __fmul_rn(q[i + j], q[i + j]));
        }
        half[h] = __fadd_rn(
            __fadd_rn(__fadd_rn(r[0], r[1]), __fadd_rn(r[2], r[3])),
            __fadd_rn(__fadd_rn(r[4], r[5]), __fadd_rn(r[6], r[7])));
    }
    outp[BN_OFF + k] = __fadd_rn(half[0], half[1]);
}

// ---- prep 2: eh/el fragment scatter, massively parallel + vectorized ------
// 32768 tasks: (k, dgroup of 8 d). The 8 shorts of one (k, dgroup) are
// CONTIGUOUS in fragment order -> one short8 store each for EH and EL.
__global__ __launch_bounds__(256) void vq_prep_scatter(const float* __restrict__ emb,
                                                       float* __restrict__ outp) {
    int task = blockIdx.x * 256 + threadIdx.x;   // 128 blocks * 256 = 32768
    int k  = task >> 5;
    int dg = task & 31;
    const float* e = emb + (size_t)k * DDIM + (dg << 3);
    float4 v0 = *(const float4*)e;
    float4 v1 = *(const float4*)(e + 4);
    float f[8] = {v0.x, v0.y, v0.z, v0.w, v1.x, v1.y, v1.z, v1.w};
    short8v hv, lv;
    #pragma unroll
    for (int j = 0; j < 8; ++j) {
        unsigned short hb = bf16_rne(f[j]);
        unsigned short lb = bf16_rne(f[j] - bf16_tf(hb));
        hv[j] = (short)hb; lv[j] = (short)lb;
    }
    int base = ((k >> 4) << 12) + ((dg >> 2) << 9) + (((k & 15) + ((dg & 3) << 4)) << 3);
    *(short8v*)((unsigned short*)(outp + EH_OFF) + base) = hv;
    *(short8v*)((unsigned short*)(outp + EL_OFF) + base) = lv;
}

// ---- An = ||z_n||^2, numpy-pairwise order (proven in round 3) -------------
__global__ __launch_bounds__(256) void vq_znorm(const float* __restrict__ z,
                                                float* __restrict__ outp) {
    const int blk = blockIdx.x;
    const int b   = blk >> 2;
    const int hw  = ((blk & 3) << 8) + threadIdx.x;
    const float* p = z + (size_t)b * CHW + hw;
    float half[2];
    #pragma unroll
    for (int h = 0; h < 2; ++h) {
        const float* q = p + (size_t)(h << 7) * HWSZ;
        float r[8];
        #pragma unroll
        for (int j = 0; j < 8; ++j) {
            float v = q[(size_t)j * HWSZ];
            r[j] = __fmul_rn(v, v);
        }
        for (int i = 8; i < 128; i += 8) {
            #pragma unroll
            for (int j = 0; j < 8; ++j) {
                float v = q[(size_t)(i + j) * HWSZ];
                r[j] = __fadd_rn(r[j], __fmul_rn(v, v));
            }
        }
        half[h] = __fadd_rn(
            __fadd_rn(__fadd_rn(r[0], r[1]), __fadd_rn(r[2], r[3])),
            __fadd_rn(__fadd_rn(r[4], r[5]), __fadd_rn(r[6], r[7])));
    }
    outp[AN_OFF + ((size_t)b << 10) + hw] = __fadd_rn(half[0], half[1]);
}

// ---- main: split-bf16 MFMA distance GEMM + top-2 argmin -------------------
__global__ __launch_bounds__(512, 2) void vq_argmin_mfma(
        const float* __restrict__ z, float* __restrict__ outp) {
    __shared__ unsigned short ZH[16384];
    __shared__ unsigned short ZL[16384];
    __shared__ unsigned short EH[8192];
    __shared__ unsigned short EL[8192];
    __shared__ float BNs[1024];
    __shared__ float REDv[2][64][16];
    __shared__ int   REDi[2][64][16];
    __shared__ float REDw[2][64][16];

    const int t = threadIdx.x;
    const int bid = blockIdx.x;
    const int nb = ((bid & 7) << 6) + (bid >> 3);   // bijective XCD swizzle
    const int b   = nb >> 3;
    const int hw0 = (nb & 7) << 7;

    const int lane = t & 63;
    const int w    = t >> 6;
    const int kwv  = w >> 1;
    const int nwv  = w & 1;
    const int l8   = lane << 3;
    const int g2   = lane >> 4;

    BNs[t] = outp[BN_OFF + t];
    BNs[t + 512] = outp[BN_OFF + t + 512];

    float an[4];
    #pragma unroll
    for (int nf = 0; nf < 4; ++nf)
        an[nf] = outp[AN_OFF + ((size_t)b << 10) + hw0 + nwv * 64 + nf * 16 + (lane & 15)];

    float mv1[4], mv2[4]; int mi1[4];
    #pragma unroll
    for (int i = 0; i < 4; ++i) { mv1[i] = 3.4e38f; mv2[i] = 3.4e38f; mi1[i] = 0x7fffffff; }

    const uint4* ehw = (const uint4*)(outp + EH_OFF);
    const uint4* elw = (const uint4*)(outp + EL_OFF);

    for (int kt = 0; kt < 4; ++kt) {
        float4v acc[4][4];
        #pragma unroll
        for (int a = 0; a < 4; ++a)
            #pragma unroll
            for (int c = 0; c < 4; ++c) acc[a][c] = (float4v){0.f, 0.f, 0.f, 0.f};

        for (int dh = 0; dh < 2; ++dh) {
            const int d0 = dh << 7;
            __syncthreads();
            // stage Z half: each lane owns ONE n and 8 consecutive d ->
            // coalesced wave loads + one ds_write_b128 per array (conflict-light)
            {
                #pragma unroll
                for (int it = 0; it < 4; ++it) {
                    int taskid = it * 8 + w;       // 0..31
                    int nhalf = taskid & 1;
                    int dg    = taskid >> 1;       // 0..15
                    int n = (nhalf << 6) + lane;
                    const float* src = z + (size_t)b * CHW
                                     + (size_t)(d0 + (dg << 3)) * HWSZ + hw0 + n;
                    float f[8];
                    #pragma unroll
                    for (int j = 0; j < 8; ++j) f[j] = src[(size_t)j * HWSZ];
                    short8v hv, lv;
                    #pragma unroll
                    for (int j = 0; j < 8; ++j) {
                        unsigned short hb = bf16_rne(f[j]);
                        unsigned short lb = bf16_rne(f[j] - bf16_tf(hb));
                        hv[j] = (short)hb; lv[j] = (short)lb;
                    }
                    int base = ((n >> 4) << 11) + ((dg >> 2) << 9)
                             + (((n & 15) + ((dg & 3) << 4)) << 3);
                    *(short8v*)&ZH[base] = hv;
                    *(short8v*)&ZL[base] = lv;
                }
            }
            for (int dc = 0; dc < 4; ++dc) {
                const int s32g = (dh << 2) + dc;
                if (dc > 0) __syncthreads();
                #pragma unroll
                for (int p = 0; p < 4; ++p) {
                    int s = t + p * 512;
                    int hl = s >> 10, ss = s & 1023;
                    int kwl = ss >> 6, ww = ss & 63;
                    const uint4* src = (hl ? elw : ehw)
                          + (size_t)(kt * 16 + kwl) * 512 + s32g * 64 + ww;
                    *(((uint4*)(hl ? EL : EH)) + ss) = *src;
                }
                __syncthreads();
                short8v ah[4], al[4], bh[4], bl[4];
                #pragma unroll
                for (int kf = 0; kf < 4; ++kf) {
                    int base = ((kwv * 4 + kf) << 9) + l8;
                    ah[kf] = *(const short8v*)&EH[base];
                    al[kf] = *(const short8v*)&EL[base];
                }
                #pragma unroll
                for (int nf = 0; nf < 4; ++nf) {
                    int base = ((nwv * 4 + nf) << 11) + (dc << 9) + l8;
                    bh[nf] = *(const short8v*)&ZH[base];
                    bl[nf] = *(const short8v*)&ZL[base];
                }
                #pragma unroll
                for (int kf = 0; kf < 4; ++kf)
                    #pragma unroll
                    for (int nf = 0; nf < 4; ++nf) {
                        acc[kf][nf] = __builtin_amdgcn_mfma_f32_16x16x32_bf16(ah[kf], bh[nf], acc[kf][nf], 0, 0, 0);
                        acc[kf][nf] = __builtin_amdgcn_mfma_f32_16x16x32_bf16(ah[kf], bl[nf], acc[kf][nf], 0, 0, 0);
                        acc[kf][nf] = __builtin_amdgcn_mfma_f32_16x16x32_bf16(al[kf], bh[nf], acc[kf][nf], 0, 0, 0);
                    }
            }
        }
        #pragma unroll
        for (int kf = 0; kf < 4; ++kf)
            #pragma unroll
            for (int nf = 0; nf < 4; ++nf)
                #pragma unroll
                for (int r = 0; r < 4; ++r) {
                    int k = kt * 256 + kwv * 64 + kf * 16 + g2 * 4 + r;
                    float s = __fsub_rn(__fadd_rn(an[nf], BNs[k]),
                                        __fmul_rn(2.0f, acc[kf][nf][r]));
                    if (s < mv1[nf] || (s == mv1[nf] && k < mi1[nf])) {
                        mv2[nf] = fminf(mv2[nf], mv1[nf]);
                        mv1[nf] = s; mi1[nf] = k;
                    } else if (s < mv2[nf]) mv2[nf] = s;
                }
    }

    #pragma unroll
    for (int nf = 0; nf < 4; ++nf) {
        int nl = nf * 16 + (lane & 15);
        int slot = kwv * 4 + g2;
        REDv[nwv][nl][slot] = mv1[nf];
        REDi[nwv][nl][slot] = mi1[nf];
        REDw[nwv][nl][slot] = mv2[nf];
    }
    __syncthreads();
    if (t < 128) {
        int nv = t >> 6, nl = t & 63;
        float bv = 3.4e38f, b2 = 3.4e38f; int bi = 0x7fffffff;
        #pragma unroll
        for (int s = 0; s < 16; ++s) {
            float v1 = REDv[nv][nl][s], v2 = REDw[nv][nl][s];
            int   i1 = REDi[nv][nl][s];
            if (v1 < bv || (v1 == bv && i1 < bi)) {
                b2 = fminf(b2, bv); bv = v1; bi = i1;
            } else b2 = fminf(b2, v1);
            b2 = fminf(b2, v2);
        }
        int n_glob = b * 1024 + hw0 + nv * 64 + nl;
        outp[IDX_OFF + n_glob] = (float)bi;
        if (b2 - bv < TAU_GAP) {
            int pos = atomicAdd((int*)(outp + CNT_OFF), 1);
            ((int*)(outp + LIST_OFF))[pos] = n_glob;
        }
    }
}

// ---- exact (f64-dot) rescore of near-tied rows, ref-bucketed scoring ------
__global__ __launch_bounds__(256) void vq_rescore(const float* __restrict__ z,
                                                  const float* __restrict__ emb,
                                                  float* __restrict__ outp) {
    const int cnt = *(const int*)(outp + CNT_OFF);
    const int t = threadIdx.x;
    __shared__ float zs[256];
    __shared__ float sv[256];
    __shared__ int   si[256];
    for (int i = blockIdx.x; i < cnt; i += gridDim.x) {
        int n = ((const int*)(outp + LIST_OFF))[i];
        int b = n >> 10, hw = n & 1023;
        __syncthreads();
        zs[t] = z[(size_t)b * CHW + (size_t)t * HWSZ + hw];
        __syncthreads();
        float An = outp[AN_OFF + n];
        float bestv = 3.4e38f; int besti = 0x7fffffff;
        #pragma unroll
        for (int kb = 0; kb < 4; ++kb) {
            int k = kb * 256 + t;
            const float4* e4 = (const float4*)(emb + (size_t)k * DDIM);
            double dot = 0.0;
            for (int q = 0; q < 64; ++q) {
                float4 v = e4[q];
                const float* zq = &zs[q << 2];
                dot += (double)v.x * zq[0] + (double)v.y * zq[1]
                     + (double)v.z * zq[2] + (double)v.w * zq[3];
            }
            float s = __fsub_rn(__fadd_rn(An, outp[BN_OFF + k]),
                                __fmul_rn(2.0f, (float)dot));
            if (s < bestv || (s == bestv && k < besti)) { bestv = s; besti = k; }
        }
        sv[t] = bestv; si[t] = besti;
        __syncthreads();
        for (int st = 128; st > 0; st >>= 1) {
            if (t < st) {
                float ov = sv[t + st]; int oi = si[t + st];
                if (ov < sv[t] || (ov == sv[t] && oi < si[t])) { sv[t] = ov; si[t] = oi; }
            }
            __syncthreads();
        }
        if (t == 0) outp[IDX_OFF + n] = (float)si[0];
    }
}

// ---- gather codebook rows, write out, loss (proven) -----------------------
__global__ __launch_bounds__(256) void vq_epilogue(const float* __restrict__ z,
                                                   const float* __restrict__ emb,
                                                   float* __restrict__ outp,
                                                   const float* __restrict__ idxf,
                                                   float* __restrict__ loss_slot) {
    const int t  = threadIdx.x;
    const int nc = blockIdx.x;
    const int b  = nc >> 4;
    const int hw = ((nc & 15) << 6) + (t & 63);
    const int n  = (b << 10) + hw;
    const int idx = (int)idxf[n];
    const float* erow = emb + (size_t)idx * DDIM;
    const size_t zb = (size_t)b * CHW + hw;

    float accl = 0.f;
    const int cbase = (t >> 6) << 2;
    #pragma unroll 4
    for (int cq = 0; cq < 16; ++cq) {
        int c = cbase + (cq << 4);
        float4 q4 = *reinterpret_cast<const float4*>(erow + c);
        float qv[4] = {q4.x, q4.y, q4.z, q4.w};
        #pragma unroll
        for (int j = 0; j < 4; ++j) {
            size_t a = zb + (size_t)(c + j) * HWSZ;
            float zv = z[a];
            outp[a] = qv[j];
            float d = qv[j] - zv;
            accl = fmaf(d, d, accl);
        }
    }
    #pragma unroll
    for (int off = 32; off > 0; off >>= 1)
        accl += __shfl_down(accl, off, 64);
    __shared__ float r[4];
    if ((t & 63) == 0) r[t >> 6] = accl;
    __syncthreads();
    if (t == 0) {
        float s = (r[0] + r[1]) + (r[2] + r[3]);
        atomicAdd(loss_slot, s * (1.25f / 16777216.f));
    }
}

extern "C" void kernel_launch(void* const* d_in, const int* in_sizes, int n_in,
                              void* d_out, int out_size, void* d_ws, size_t ws_size,
                              hipStream_t stream) {
    const float* z   = (const float*)d_in[0];
    const float* emb = (const float*)d_in[1];
    float* out       = (float*)d_out;

    vq_prep_bn     <<<dim3(4),    dim3(256), 0, stream>>>(emb, out);
    vq_prep_scatter<<<dim3(128),  dim3(256), 0, stream>>>(emb, out);
    vq_znorm       <<<dim3(256),  dim3(256), 0, stream>>>(z, out);
    vq_argmin_mfma <<<dim3(512),  dim3(512), 0, stream>>>(z, out);
    vq_rescore     <<<dim3(256),  dim3(256), 0, stream>>>(z, emb, out);
    vq_epilogue    <<<dim3(1024), dim3(256), 0, stream>>>(z, emb, out,
                                                          out + IDX_OFF, out + LOSS_OFF);
}

// Round 6
// 364.734 us; speedup vs baseline: 1.4073x; 1.0660x over previous
//
#include <hip/hip_runtime.h>
#include <math.h>

#define KCODES 1024
#define DDIM   256
#define HWSZ   1024
#define CHW    262144
#define LOSS_OFF 16777216
#define IDX_OFF  16777217
#define TAU_GAP  1e-4f

// ---- path B (fallback) scratch offsets inside d_out (f32 words) ----
#define EH_OFF   1000000
#define EL_OFF   1200000
#define AN_OFF   1400000
#define BN_OFF   1500000
#define LIST_OFF 1550000
#define CNT_OFF  1650000

// ---- path A ws byte offsets ----
#define WS_EH   0
#define WS_EL   524288
#define WS_AN   1048576
#define WS_BN   1310720
#define WS_LIST 1314816
#define WS_CNT  1576960
#define WS_NEED 1576964

typedef __attribute__((ext_vector_type(8))) short short8v;
typedef __attribute__((ext_vector_type(4))) float float4v;

static __device__ __forceinline__ unsigned short bf16_rne(float f) {
    unsigned u = __float_as_uint(f);
    return (unsigned short)((u + 0x7FFFu + ((u >> 16) & 1u)) >> 16);
}
static __device__ __forceinline__ float bf16_tf(unsigned short h) {
    return __uint_as_float(((unsigned)h) << 16);
}

// ---- Bn = ||e_k||^2 (ref pairwise order) + zero cnt/loss ------------------
__global__ __launch_bounds__(64) void vq_prep_bn(const float* __restrict__ emb,
                                                 float* __restrict__ Bn,
                                                 float* __restrict__ loss_slot,
                                                 int* __restrict__ cnt) {
    int k = blockIdx.x * 64 + threadIdx.x;
    if (k == 0) { *cnt = 0; loss_slot[0] = 0.f; }
    if (k >= KCODES) return;
    const float* e = emb + (size_t)k * DDIM;
    float half[2];
    #pragma unroll
    for (int h = 0; h < 2; ++h) {
        const float* q = e + (h << 7);
        float r[8];
        #pragma unroll
        for (int j = 0; j < 8; ++j) r[j] = __fmul_rn(q[j], q[j]);
        for (int i = 8; i < 128; i += 8) {
            #pragma unroll
            for (int j = 0; j < 8; ++j)
                r[j] = __fadd_rn(r[j], __fmul_rn(q[i + j], q[i + j]));
        }
        half[h] = __fadd_rn(
            __fadd_rn(__fadd_rn(r[0], r[1]), __fadd_rn(r[2], r[3])),
            __fadd_rn(__fadd_rn(r[4], r[5]), __fadd_rn(r[6], r[7])));
    }
    Bn[k] = __fadd_rn(half[0], half[1]);
}

// ---- E hi/lo fragment scatter (layout proven in r5) -----------------------
__global__ __launch_bounds__(256) void vq_prep_scatter(const float* __restrict__ emb,
                                                       unsigned short* __restrict__ EHg,
                                                       unsigned short* __restrict__ ELg) {
    int task = blockIdx.x * 256 + threadIdx.x;   // 32768 tasks
    int k  = task >> 5;
    int dg = task & 31;
    const float* e = emb + (size_t)k * DDIM + (dg << 3);
    float4 v0 = *(const float4*)e;
    float4 v1 = *(const float4*)(e + 4);
    float f[8] = {v0.x, v0.y, v0.z, v0.w, v1.x, v1.y, v1.z, v1.w};
    short8v hv, lv;
    #pragma unroll
    for (int j = 0; j < 8; ++j) {
        unsigned short hb = bf16_rne(f[j]);
        unsigned short lb = bf16_rne(f[j] - bf16_tf(hb));
        hv[j] = (short)hb; lv[j] = (short)lb;
    }
    int base = ((k >> 4) << 12) + ((dg >> 2) << 9) + (((k & 15) + ((dg & 3) << 4)) << 3);
    *(short8v*)(EHg + base) = hv;
    *(short8v*)(ELg + base) = lv;
}

// ---- path A: An (ref pairwise order) + z hi/lo pre-convert, fused ---------
// 512 blocks (one per 128-n tile), 256 threads: t<128 -> d 0..127 of n=t,
// t>=128 -> d 128..255 of n=t-128. One pass over z.
__global__ __launch_bounds__(256) void vq_zprep(const float* __restrict__ z,
                                                unsigned short* __restrict__ ZHg,
                                                unsigned short* __restrict__ ZLg,
                                                float* __restrict__ An) {
    __shared__ float hsum[2][128];
    const int t  = threadIdx.x;
    const int nb = blockIdx.x;
    const int b  = nb >> 3, hw0 = (nb & 7) << 7;
    const int half = t >> 7;
    const int n    = t & 127;
    const float* src = z + (size_t)b * CHW + (size_t)(half << 7) * HWSZ + hw0 + n;
    const int ng = n >> 4, m = n & 15;
    unsigned short* dh = ZHg + (size_t)nb * 32768 + (ng << 12) + (m << 3);
    unsigned short* dl = ZLg + (size_t)nb * 32768 + (ng << 12) + (m << 3);
    float r[8];
    #pragma unroll
    for (int dg = 0; dg < 16; ++dg) {
        float f[8];
        #pragma unroll
        for (int j = 0; j < 8; ++j) f[j] = src[(size_t)((dg << 3) + j) * HWSZ];
        short8v hv, lv;
        #pragma unroll
        for (int j = 0; j < 8; ++j) {
            unsigned short hb = bf16_rne(f[j]);
            unsigned short lb = bf16_rne(f[j] - bf16_tf(hb));
            hv[j] = (short)hb; lv[j] = (short)lb;
        }
        int dglob = (half << 4) + dg;          // 0..31
        int s32 = dglob >> 2, g = dglob & 3;
        *(short8v*)(dh + (s32 << 9) + (g << 7)) = hv;
        *(short8v*)(dl + (s32 << 9) + (g << 7)) = lv;
        if (dg == 0) {
            #pragma unroll
            for (int j = 0; j < 8; ++j) r[j] = __fmul_rn(f[j], f[j]);
        } else {
            #pragma unroll
            for (int j = 0; j < 8; ++j) r[j] = __fadd_rn(r[j], __fmul_rn(f[j], f[j]));
        }
    }
    hsum[half][n] = __fadd_rn(
        __fadd_rn(__fadd_rn(r[0], r[1]), __fadd_rn(r[2], r[3])),
        __fadd_rn(__fadd_rn(r[4], r[5]), __fadd_rn(r[6], r[7])));
    __syncthreads();
    if (t < 128) An[nb * 128 + t] = __fadd_rn(hsum[0][t], hsum[1][t]);
}

// ---- path B: An only (r3-proven) ------------------------------------------
__global__ __launch_bounds__(256) void vq_znorm(const float* __restrict__ z,
                                                float* __restrict__ An) {
    const int blk = blockIdx.x;
    const int b   = blk >> 2;
    const int hw  = ((blk & 3) << 8) + threadIdx.x;
    const float* p = z + (size_t)b * CHW + hw;
    float half[2];
    #pragma unroll
    for (int h = 0; h < 2; ++h) {
        const float* q = p + (size_t)(h << 7) * HWSZ;
        float r[8];
        #pragma unroll
        for (int j = 0; j < 8; ++j) { float v = q[(size_t)j * HWSZ]; r[j] = __fmul_rn(v, v); }
        for (int i = 8; i < 128; i += 8) {
            #pragma unroll
            for (int j = 0; j < 8; ++j) {
                float v = q[(size_t)(i + j) * HWSZ];
                r[j] = __fadd_rn(r[j], __fmul_rn(v, v));
            }
        }
        half[h] = __fadd_rn(
            __fadd_rn(__fadd_rn(r[0], r[1]), __fadd_rn(r[2], r[3])),
            __fadd_rn(__fadd_rn(r[4], r[5]), __fadd_rn(r[6], r[7])));
    }
    An[((size_t)b << 10) + hw] = __fadd_rn(half[0], half[1]);
}

// ---- shared epilogue tail: top-2/argmin block reduction + loss ------------
static __device__ __forceinline__ void argmin_tail(
        float mv1[4], float mv2[4], int mi1[4],
        float* REDv, int* REDi, float* REDw,
        int t, int lane, int kwv, int nwv, int g2, int nb,
        float* idx_out, int* list, int* cnt, float* loss_slot) {
    #pragma unroll
    for (int nf = 0; nf < 4; ++nf) {
        int nl = nf * 16 + (lane & 15);
        int slot = kwv * 4 + g2;
        REDv[(nwv * 64 + nl) * 16 + slot] = mv1[nf];
        REDi[(nwv * 64 + nl) * 16 + slot] = mi1[nf];
        REDw[(nwv * 64 + nl) * 16 + slot] = mv2[nf];
    }
    __syncthreads();
    if (t < 128) {
        int nv = t >> 6, nl = t & 63;
        float bv = 3.4e38f, b2 = 3.4e38f; int bi = 0x7fffffff;
        #pragma unroll
        for (int s = 0; s < 16; ++s) {
            float v1 = REDv[(nv * 64 + nl) * 16 + s];
            float v2 = REDw[(nv * 64 + nl) * 16 + s];
            int   i1 = REDi[(nv * 64 + nl) * 16 + s];
            if (v1 < bv || (v1 == bv && i1 < bi)) { b2 = fminf(b2, bv); bv = v1; bi = i1; }
            else b2 = fminf(b2, v1);
            b2 = fminf(b2, v2);
        }
        int n_glob = nb * 128 + nv * 64 + nl;
        idx_out[n_glob] = (float)bi;
        if (b2 - bv < TAU_GAP) {
            int pos = atomicAdd(cnt, 1);
            list[pos] = n_glob;
        }
        // loss: sum of winning (bucketed) distances == sum ||q-z||^2
        float lsum = bv;
        #pragma unroll
        for (int off = 32; off > 0; off >>= 1)
            lsum += __shfl_down(lsum, off, 64);
        if ((t & 63) == 0) atomicAdd(loss_slot, lsum * (1.25f / 16777216.f));
    }
}

// ---- path A main: pre-converted MFMA GEMM + argmin, 68KB LDS, 2 blk/CU ----
__global__ __launch_bounds__(512, 4) void vq_argmin_pre(
        const unsigned short* __restrict__ ZHg, const unsigned short* __restrict__ ZLg,
        const unsigned short* __restrict__ EHg, const unsigned short* __restrict__ ELg,
        const float* __restrict__ An, const float* __restrict__ Bn,
        float* __restrict__ idx_out, int* __restrict__ list, int* __restrict__ cnt,
        float* __restrict__ loss_slot) {
    __shared__ uint4 ZH4[1024], ZL4[1024];     // 16KB each: 128n x 64d
    __shared__ uint4 EBUF4[2048];              // 32KB: E chunk; RED alias after k-loop
    __shared__ float BNs[1024];
    unsigned short* ZH = (unsigned short*)ZH4;
    unsigned short* ZL = (unsigned short*)ZL4;
    unsigned short* EH = (unsigned short*)EBUF4;
    unsigned short* EL = EH + 8192;

    const int t = threadIdx.x;
    const int bid = blockIdx.x;
    const int nb = ((bid & 7) << 6) + (bid >> 3);   // bijective XCD swizzle
    const int lane = t & 63, w = t >> 6;
    const int kwv = w >> 1, nwv = w & 1;
    const int l8 = lane << 3, g2 = lane >> 4;

    BNs[t] = Bn[t];
    BNs[t + 512] = Bn[t + 512];

    float an[4];
    #pragma unroll
    for (int nf = 0; nf < 4; ++nf)
        an[nf] = An[nb * 128 + nwv * 64 + nf * 16 + (lane & 15)];

    float mv1[4], mv2[4]; int mi1[4];
    #pragma unroll
    for (int i = 0; i < 4; ++i) { mv1[i] = 3.4e38f; mv2[i] = 3.4e38f; mi1[i] = 0x7fffffff; }

    const uint4* zh4 = (const uint4*)ZHg + (size_t)nb * 4096;
    const uint4* zl4 = (const uint4*)ZLg + (size_t)nb * 4096;
    const uint4* eh4 = (const uint4*)EHg;
    const uint4* el4 = (const uint4*)ELg;

    for (int kt = 0; kt < 4; ++kt) {
        float4v acc[4][4];
        #pragma unroll
        for (int a = 0; a < 4; ++a)
            #pragma unroll
            for (int c = 0; c < 4; ++c) acc[a][c] = (float4v){0.f, 0.f, 0.f, 0.f};

        for (int dh = 0; dh < 4; ++dh) {
            __syncthreads();   // previous Z/E readers done
            #pragma unroll
            for (int p = 0; p < 4; ++p) {       // stage Z 64-d chunk: 2048 uint4
                int s = p * 512 + t;
                int arr = s >> 10, ss = s & 1023;
                int ng = ss >> 7, sl = (ss >> 6) & 1, ww = ss & 63;
                const uint4* src = (arr ? zl4 : zh4) + ng * 512 + ((dh << 1) + sl) * 64 + ww;
                (arr ? ZL4 : ZH4)[ss] = *src;
            }
            for (int dc = 0; dc < 2; ++dc) {
                const int s32 = (dh << 1) + dc;
                if (dc) __syncthreads();        // E(dc=0) readers done
                #pragma unroll
                for (int p = 0; p < 4; ++p) {   // stage E 32-d chunk: 2048 uint4
                    int s = p * 512 + t;
                    int arr = s >> 10, ss = s & 1023;
                    int kwl = ss >> 6, ww = ss & 63;
                    const uint4* src = (arr ? el4 : eh4)
                        + (size_t)(((kt << 4) + kwl) << 9) + (s32 << 6) + ww;
                    (arr ? ((uint4*)EL) : ((uint4*)EH))[ss] = *src;
                }
                __syncthreads();
                short8v ah[4], al[4], bh[4], bl[4];
                #pragma unroll
                for (int kf = 0; kf < 4; ++kf) {
                    int base = ((kwv * 4 + kf) << 9) + l8;
                    ah[kf] = *(const short8v*)&EH[base];
                    al[kf] = *(const short8v*)&EL[base];
                }
                #pragma unroll
                for (int nf = 0; nf < 4; ++nf) {
                    int base = ((nwv * 4 + nf) << 10) + (dc << 9) + l8;
                    bh[nf] = *(const short8v*)&ZH[base];
                    bl[nf] = *(const short8v*)&ZL[base];
                }
                #pragma unroll
                for (int kf = 0; kf < 4; ++kf)
                    #pragma unroll
                    for (int nf = 0; nf < 4; ++nf) {
                        acc[kf][nf] = __builtin_amdgcn_mfma_f32_16x16x32_bf16(ah[kf], bh[nf], acc[kf][nf], 0, 0, 0);
                        acc[kf][nf] = __builtin_amdgcn_mfma_f32_16x16x32_bf16(ah[kf], bl[nf], acc[kf][nf], 0, 0, 0);
                        acc[kf][nf] = __builtin_amdgcn_mfma_f32_16x16x32_bf16(al[kf], bh[nf], acc[kf][nf], 0, 0, 0);
                    }
            }
        }
        #pragma unroll
        for (int kf = 0; kf < 4; ++kf)
            #pragma unroll
            for (int nf = 0; nf < 4; ++nf)
                #pragma unroll
                for (int r = 0; r < 4; ++r) {
                    int k = kt * 256 + kwv * 64 + kf * 16 + g2 * 4 + r;
                    float s = __fsub_rn(__fadd_rn(an[nf], BNs[k]),
                                        __fmul_rn(2.0f, acc[kf][nf][r]));
                    if (s < mv1[nf] || (s == mv1[nf] && k < mi1[nf])) {
                        mv2[nf] = fminf(mv2[nf], mv1[nf]);
                        mv1[nf] = s; mi1[nf] = k;
                    } else if (s < mv2[nf]) mv2[nf] = s;
                }
    }

    __syncthreads();   // done reading EBUF as E -> safe to alias as RED
    float* REDv = (float*)EBUF4;
    int*   REDi = (int*)((char*)EBUF4 + 8192);
    float* REDw = (float*)((char*)EBUF4 + 16384);
    argmin_tail(mv1, mv2, mi1, REDv, REDi, REDw, t, lane, kwv, nwv, g2, nb,
                idx_out, list, cnt, loss_slot);
}

// ---- path B main: r5-proven conversion-in-kernel version (+loss) ----------
__global__ __launch_bounds__(512, 2) void vq_argmin_conv(
        const float* __restrict__ z,
        const unsigned short* __restrict__ EHg, const unsigned short* __restrict__ ELg,
        const float* __restrict__ An, const float* __restrict__ Bn,
        float* __restrict__ idx_out, int* __restrict__ list, int* __restrict__ cnt,
        float* __restrict__ loss_slot) {
    __shared__ unsigned short ZH[16384];
    __shared__ unsigned short ZL[16384];
    __shared__ unsigned short EH[8192];
    __shared__ unsigned short EL[8192];
    __shared__ float BNs[1024];
    __shared__ float REDv[2048];
    __shared__ int   REDi[2048];
    __shared__ float REDw[2048];

    const int t = threadIdx.x;
    const int bid = blockIdx.x;
    const int nb = ((bid & 7) << 6) + (bid >> 3);
    const int b   = nb >> 3;
    const int hw0 = (nb & 7) << 7;
    const int lane = t & 63, w = t >> 6;
    const int kwv = w >> 1, nwv = w & 1;
    const int l8 = lane << 3, g2 = lane >> 4;

    BNs[t] = Bn[t];
    BNs[t + 512] = Bn[t + 512];

    float an[4];
    #pragma unroll
    for (int nf = 0; nf < 4; ++nf)
        an[nf] = An[nb * 128 + nwv * 64 + nf * 16 + (lane & 15)];

    float mv1[4], mv2[4]; int mi1[4];
    #pragma unroll
    for (int i = 0; i < 4; ++i) { mv1[i] = 3.4e38f; mv2[i] = 3.4e38f; mi1[i] = 0x7fffffff; }

    const uint4* ehw = (const uint4*)EHg;
    const uint4* elw = (const uint4*)ELg;

    for (int kt = 0; kt < 4; ++kt) {
        float4v acc[4][4];
        #pragma unroll
        for (int a = 0; a < 4; ++a)
            #pragma unroll
            for (int c = 0; c < 4; ++c) acc[a][c] = (float4v){0.f, 0.f, 0.f, 0.f};

        for (int dh = 0; dh < 2; ++dh) {
            const int d0 = dh << 7;
            __syncthreads();
            {
                #pragma unroll
                for (int it = 0; it < 4; ++it) {
                    int taskid = it * 8 + w;
                    int nhalf = taskid & 1;
                    int dg    = taskid >> 1;
                    int n = (nhalf << 6) + lane;
                    const float* src = z + (size_t)b * CHW
                                     + (size_t)(d0 + (dg << 3)) * HWSZ + hw0 + n;
                    float f[8];
                    #pragma unroll
                    for (int j = 0; j < 8; ++j) f[j] = src[(size_t)j * HWSZ];
                    short8v hv, lv;
                    #pragma unroll
                    for (int j = 0; j < 8; ++j) {
                        unsigned short hb = bf16_rne(f[j]);
                        unsigned short lb = bf16_rne(f[j] - bf16_tf(hb));
                        hv[j] = (short)hb; lv[j] = (short)lb;
                    }
                    int base = ((n >> 4) << 11) + ((dg >> 2) << 9)
                             + (((n & 15) + ((dg & 3) << 4)) << 3);
                    *(short8v*)&ZH[base] = hv;
                    *(short8v*)&ZL[base] = lv;
                }
            }
            for (int dc = 0; dc < 4; ++dc) {
                const int s32g = (dh << 2) + dc;
                if (dc > 0) __syncthreads();
                #pragma unroll
                for (int p = 0; p < 4; ++p) {
                    int s = t + p * 512;
                    int hl = s >> 10, ss = s & 1023;
                    int kwl = ss >> 6, ww = ss & 63;
                    const uint4* src = (hl ? elw : ehw)
                          + (size_t)(kt * 16 + kwl) * 512 + s32g * 64 + ww;
                    *(((uint4*)(hl ? EL : EH)) + ss) = *src;
                }
                __syncthreads();
                short8v ah[4], al[4], bh[4], bl[4];
                #pragma unroll
                for (int kf = 0; kf < 4; ++kf) {
                    int base = ((kwv * 4 + kf) << 9) + l8;
                    ah[kf] = *(const short8v*)&EH[base];
                    al[kf] = *(const short8v*)&EL[base];
                }
                #pragma unroll
                for (int nf = 0; nf < 4; ++nf) {
                    int base = ((nwv * 4 + nf) << 11) + (dc << 9) + l8;
                    bh[nf] = *(const short8v*)&ZH[base];
                    bl[nf] = *(const short8v*)&ZL[base];
                }
                #pragma unroll
                for (int kf = 0; kf < 4; ++kf)
                    #pragma unroll
                    for (int nf = 0; nf < 4; ++nf) {
                        acc[kf][nf] = __builtin_amdgcn_mfma_f32_16x16x32_bf16(ah[kf], bh[nf], acc[kf][nf], 0, 0, 0);
                        acc[kf][nf] = __builtin_amdgcn_mfma_f32_16x16x32_bf16(ah[kf], bl[nf], acc[kf][nf], 0, 0, 0);
                        acc[kf][nf] = __builtin_amdgcn_mfma_f32_16x16x32_bf16(al[kf], bh[nf], acc[kf][nf], 0, 0, 0);
                    }
            }
        }
        #pragma unroll
        for (int kf = 0; kf < 4; ++kf)
            #pragma unroll
            for (int nf = 0; nf < 4; ++nf)
                #pragma unroll
                for (int r = 0; r < 4; ++r) {
                    int k = kt * 256 + kwv * 64 + kf * 16 + g2 * 4 + r;
                    float s = __fsub_rn(__fadd_rn(an[nf], BNs[k]),
                                        __fmul_rn(2.0f, acc[kf][nf][r]));
                    if (s < mv1[nf] || (s == mv1[nf] && k < mi1[nf])) {
                        mv2[nf] = fminf(mv2[nf], mv1[nf]);
                        mv1[nf] = s; mi1[nf] = k;
                    } else if (s < mv2[nf]) mv2[nf] = s;
                }
    }
    __syncthreads();
    argmin_tail(mv1, mv2, mi1, REDv, REDi, REDw, t, lane, kwv, nwv, g2, nb,
                idx_out, list, cnt, loss_slot);
}

// ---- exact (f64-dot) rescore of near-tied rows ----------------------------
__global__ __launch_bounds__(256) void vq_rescore(const float* __restrict__ z,
                                                  const float* __restrict__ emb,
                                                  const float* __restrict__ An,
                                                  const float* __restrict__ Bn,
                                                  float* __restrict__ idx_out,
                                                  const int* __restrict__ list,
                                                  const int* __restrict__ cnt) {
    const int c = *cnt;
    const int t = threadIdx.x;
    __shared__ float zs[256];
    __shared__ float sv[256];
    __shared__ int   si[256];
    for (int i = blockIdx.x; i < c; i += gridDim.x) {
        int n = list[i];
        int b = n >> 10, hw = n & 1023;
        __syncthreads();
        zs[t] = z[(size_t)b * CHW + (size_t)t * HWSZ + hw];
        __syncthreads();
        float Anv = An[n];
        float bestv = 3.4e38f; int besti = 0x7fffffff;
        #pragma unroll
        for (int kb = 0; kb < 4; ++kb) {
            int k = kb * 256 + t;
            const float4* e4 = (const float4*)(emb + (size_t)k * DDIM);
            double dot = 0.0;
            for (int q = 0; q < 64; ++q) {
                float4 v = e4[q];
                const float* zq = &zs[q << 2];
                dot += (double)v.x * zq[0] + (double)v.y * zq[1]
                     + (double)v.z * zq[2] + (double)v.w * zq[3];
            }
            float s = __fsub_rn(__fadd_rn(Anv, Bn[k]),
                                __fmul_rn(2.0f, (float)dot));
            if (s < bestv || (s == bestv && k < besti)) { bestv = s; besti = k; }
        }
        sv[t] = bestv; si[t] = besti;
        __syncthreads();
        for (int st = 128; st > 0; st >>= 1) {
            if (t < st) {
                float ov = sv[t + st]; int oi = si[t + st];
                if (ov < sv[t] || (ov == sv[t] && oi < si[t])) { sv[t] = ov; si[t] = oi; }
            }
            __syncthreads();
        }
        if (t == 0) idx_out[n] = (float)si[0];
    }
}

// ---- gather codebook rows -> out (no z read; loss computed in argmin) -----
__global__ __launch_bounds__(256) void vq_epilogue(const float* __restrict__ emb,
                                                   float* __restrict__ outp,
                                                   const float* __restrict__ idxf) {
    const int t  = threadIdx.x;
    const int nc = blockIdx.x;
    const int b  = nc >> 4;
    const int hw = ((nc & 15) << 6) + (t & 63);
    const int n  = (b << 10) + hw;
    const int idx = (int)idxf[n];
    const float* erow = emb + (size_t)idx * DDIM;
    const size_t zb = (size_t)b * CHW + hw;

    const int cbase = (t >> 6) << 2;
    #pragma unroll 4
    for (int cq = 0; cq < 16; ++cq) {
        int c = cbase + (cq << 4);
        float4 q4 = *reinterpret_cast<const float4*>(erow + c);
        outp[zb + (size_t)(c + 0) * HWSZ] = q4.x;
        outp[zb + (size_t)(c + 1) * HWSZ] = q4.y;
        outp[zb + (size_t)(c + 2) * HWSZ] = q4.z;
        outp[zb + (size_t)(c + 3) * HWSZ] = q4.w;
    }
}

extern "C" void kernel_launch(void* const* d_in, const int* in_sizes, int n_in,
                              void* d_out, int out_size, void* d_ws, size_t ws_size,
                              hipStream_t stream) {
    const float* z   = (const float*)d_in[0];
    const float* emb = (const float*)d_in[1];
    float* out       = (float*)d_out;
    float* loss_slot = out + LOSS_OFF;
    float* idx_out   = out + IDX_OFF;

    if (ws_size >= (size_t)WS_NEED) {
        // path A: E/An/Bn/list/cnt in ws; z hi/lo fills the whole out region
        char* ws = (char*)d_ws;
        unsigned short* EHg = (unsigned short*)(ws + WS_EH);
        unsigned short* ELg = (unsigned short*)(ws + WS_EL);
        float* An = (float*)(ws + WS_AN);
        float* Bn = (float*)(ws + WS_BN);
        int*  list = (int*)(ws + WS_LIST);
        int*  cnt  = (int*)(ws + WS_CNT);
        unsigned short* ZHg = (unsigned short*)d_out;
        unsigned short* ZLg = ZHg + 16777216;

        vq_prep_bn     <<<dim3(16),   dim3(64),  0, stream>>>(emb, Bn, loss_slot, cnt);
        vq_prep_scatter<<<dim3(128),  dim3(256), 0, stream>>>(emb, EHg, ELg);
        vq_zprep       <<<dim3(512),  dim3(256), 0, stream>>>(z, ZHg, ZLg, An);
        vq_argmin_pre  <<<dim3(512),  dim3(512), 0, stream>>>(ZHg, ZLg, EHg, ELg, An, Bn,
                                                              idx_out, list, cnt, loss_slot);
        vq_rescore     <<<dim3(1024), dim3(256), 0, stream>>>(z, emb, An, Bn, idx_out, list, cnt);
        vq_epilogue    <<<dim3(1024), dim3(256), 0, stream>>>(emb, out, idx_out);
    } else {
        // path B: everything in the out region (r5-proven layout)
        unsigned short* EHg = (unsigned short*)(out + EH_OFF);
        unsigned short* ELg = (unsigned short*)(out + EL_OFF);
        float* An = out + AN_OFF;
        float* Bn = out + BN_OFF;
        int*  list = (int*)(out + LIST_OFF);
        int*  cnt  = (int*)(out + CNT_OFF);

        vq_prep_bn     <<<dim3(16),   dim3(64),  0, stream>>>(emb, Bn, loss_slot, cnt);
        vq_prep_scatter<<<dim3(128),  dim3(256), 0, stream>>>(emb, EHg, ELg);
        vq_znorm       <<<dim3(256),  dim3(256), 0, stream>>>(z, An);
        vq_argmin_conv <<<dim3(512),  dim3(512), 0, stream>>>(z, EHg, ELg, An, Bn,
                                                              idx_out, list, cnt, loss_slot);
        vq_rescore     <<<dim3(1024), dim3(256), 0, stream>>>(z, emb, An, Bn, idx_out, list, cnt);
        vq_epilogue    <<<dim3(1024), dim3(256), 0, stream>>>(emb, out, idx_out);
    }
}

// Round 7
// 321.352 us; speedup vs baseline: 1.5973x; 1.1350x over previous
//
#include <hip/hip_runtime.h>
#include <math.h>

#define KCODES 1024
#define DDIM   256
#define HWSZ   1024
#define CHW    262144
#define LOSS_OFF 16777216
#define IDX_OFF  16777217
#define TAU_GAP  1e-4f

// ---- path B (fallback) scratch offsets inside d_out (f32 words) ----
#define EH_OFF   1000000
#define EL_OFF   1200000
#define AN_OFF   1400000
#define BN_OFF   1500000
#define LIST_OFF 1550000
#define CNT_OFF  1650000

// ---- path A ws byte offsets ----
#define WS_EH   0
#define WS_EL   524288
#define WS_AN   1048576
#define WS_BN   1310720
#define WS_LIST 1314816
#define WS_CNT  1576960
#define WS_NEED 1576964

typedef __attribute__((ext_vector_type(8))) short short8v;
typedef __attribute__((ext_vector_type(4))) float float4v;

static __device__ __forceinline__ unsigned short bf16_rne(float f) {
    unsigned u = __float_as_uint(f);
    return (unsigned short)((u + 0x7FFFu + ((u >> 16) & 1u)) >> 16);
}
static __device__ __forceinline__ float bf16_tf(unsigned short h) {
    return __uint_as_float(((unsigned)h) << 16);
}

// ---- Bn = ||e_k||^2 (ref pairwise order) + zero cnt/loss ------------------
__global__ __launch_bounds__(64) void vq_prep_bn(const float* __restrict__ emb,
                                                 float* __restrict__ Bn,
                                                 float* __restrict__ loss_slot,
                                                 int* __restrict__ cnt) {
    int k = blockIdx.x * 64 + threadIdx.x;
    if (k == 0) { *cnt = 0; loss_slot[0] = 0.f; }
    if (k >= KCODES) return;
    const float* e = emb + (size_t)k * DDIM;
    float half[2];
    #pragma unroll
    for (int h = 0; h < 2; ++h) {
        const float* q = e + (h << 7);
        float r[8];
        #pragma unroll
        for (int j = 0; j < 8; ++j) r[j] = __fmul_rn(q[j], q[j]);
        for (int i = 8; i < 128; i += 8) {
            #pragma unroll
            for (int j = 0; j < 8; ++j)
                r[j] = __fadd_rn(r[j], __fmul_rn(q[i + j], q[i + j]));
        }
        half[h] = __fadd_rn(
            __fadd_rn(__fadd_rn(r[0], r[1]), __fadd_rn(r[2], r[3])),
            __fadd_rn(__fadd_rn(r[4], r[5]), __fadd_rn(r[6], r[7])));
    }
    Bn[k] = __fadd_rn(half[0], half[1]);
}

// ---- E hi/lo fragment scatter (layout proven in r5/r6) --------------------
__global__ __launch_bounds__(256) void vq_prep_scatter(const float* __restrict__ emb,
                                                       unsigned short* __restrict__ EHg,
                                                       unsigned short* __restrict__ ELg) {
    int task = blockIdx.x * 256 + threadIdx.x;   // 32768 tasks
    int k  = task >> 5;
    int dg = task & 31;
    const float* e = emb + (size_t)k * DDIM + (dg << 3);
    float4 v0 = *(const float4*)e;
    float4 v1 = *(const float4*)(e + 4);
    float f[8] = {v0.x, v0.y, v0.z, v0.w, v1.x, v1.y, v1.z, v1.w};
    short8v hv, lv;
    #pragma unroll
    for (int j = 0; j < 8; ++j) {
        unsigned short hb = bf16_rne(f[j]);
        unsigned short lb = bf16_rne(f[j] - bf16_tf(hb));
        hv[j] = (short)hb; lv[j] = (short)lb;
    }
    int base = ((k >> 4) << 12) + ((dg >> 2) << 9) + (((k & 15) + ((dg & 3) << 4)) << 3);
    *(short8v*)(EHg + base) = hv;
    *(short8v*)(ELg + base) = lv;
}

// ---- An = ||z_n||^2, numpy-pairwise order (r3-proven) ---------------------
__global__ __launch_bounds__(256) void vq_znorm(const float* __restrict__ z,
                                                float* __restrict__ An) {
    const int blk = blockIdx.x;
    const int b   = blk >> 2;
    const int hw  = ((blk & 3) << 8) + threadIdx.x;
    const float* p = z + (size_t)b * CHW + hw;
    float half[2];
    #pragma unroll
    for (int h = 0; h < 2; ++h) {
        const float* q = p + (size_t)(h << 7) * HWSZ;
        float r[8];
        #pragma unroll
        for (int j = 0; j < 8; ++j) { float v = q[(size_t)j * HWSZ]; r[j] = __fmul_rn(v, v); }
        for (int i = 8; i < 128; i += 8) {
            #pragma unroll
            for (int j = 0; j < 8; ++j) {
                float v = q[(size_t)(i + j) * HWSZ];
                r[j] = __fadd_rn(r[j], __fmul_rn(v, v));
            }
        }
        half[h] = __fadd_rn(
            __fadd_rn(__fadd_rn(r[0], r[1]), __fadd_rn(r[2], r[3])),
            __fadd_rn(__fadd_rn(r[4], r[5]), __fadd_rn(r[6], r[7])));
    }
    An[((size_t)b << 10) + hw] = __fadd_rn(half[0], half[1]);
}

// ---- main: in-kernel-convert MFMA GEMM + argmin, 68KB LDS, 2 blk/CU -------
// WRITE_OUT: also gather emb[idx] rows into out (path A; epilogue fused).
template<bool WRITE_OUT>
__global__ __launch_bounds__(512, 4) void vq_argmin_conv(
        const float* __restrict__ z,
        const unsigned short* __restrict__ EHg, const unsigned short* __restrict__ ELg,
        const float* __restrict__ An, const float* __restrict__ Bn,
        float* __restrict__ idx_out, int* __restrict__ list, int* __restrict__ cnt,
        float* __restrict__ loss_slot, float* __restrict__ outp,
        const float* __restrict__ emb) {
    __shared__ uint4 ZH4[1024], ZL4[1024];   // 16 KB each: 128n x 64d hi/lo
    __shared__ uint4 EBUF4[2048];            // 32 KB: E chunk; RED/FIDX alias later
    __shared__ float BNs[1024];              // 4 KB
    unsigned short* ZH = (unsigned short*)ZH4;
    unsigned short* ZL = (unsigned short*)ZL4;
    unsigned short* EH = (unsigned short*)EBUF4;
    unsigned short* EL = EH + 8192;

    const int t = threadIdx.x;
    const int bid = blockIdx.x;
    const int nb = ((bid & 7) << 6) + (bid >> 3);   // bijective XCD swizzle (512%8==0)
    const int b   = nb >> 3;
    const int hw0 = (nb & 7) << 7;
    const int lane = t & 63, w = t >> 6;
    const int kwv = w >> 1, nwv = w & 1;
    const int l8 = lane << 3, g2 = lane >> 4;

    BNs[t] = Bn[t];
    BNs[t + 512] = Bn[t + 512];

    float an[4];
    #pragma unroll
    for (int nf = 0; nf < 4; ++nf)
        an[nf] = An[nb * 128 + nwv * 64 + nf * 16 + (lane & 15)];

    float mv1[4], mv2[4]; int mi1[4];
    #pragma unroll
    for (int i = 0; i < 4; ++i) { mv1[i] = 3.4e38f; mv2[i] = 3.4e38f; mi1[i] = 0x7fffffff; }

    const uint4* eh4 = (const uint4*)EHg;
    const uint4* el4 = (const uint4*)ELg;

    for (int kt = 0; kt < 4; ++kt) {
        float4v acc[4][4];
        #pragma unroll
        for (int a = 0; a < 4; ++a)
            #pragma unroll
            for (int c = 0; c < 4; ++c) acc[a][c] = (float4v){0.f, 0.f, 0.f, 0.f};

        for (int dh = 0; dh < 4; ++dh) {
            const int d0 = dh << 6;
            __syncthreads();                 // prior readers of Z and E done
            // stage Z 64-d chunk: convert f32 -> hi/lo bf16, fragment order.
            // 1024 tasks (n 0..127 x dg 0..7), 2 per thread; coalesced loads.
            #pragma unroll
            for (int it = 0; it < 2; ++it) {
                int tau = it * 512 + t;
                int n  = tau & 127;
                int dg = tau >> 7;           // 0..7
                const float* src = z + (size_t)b * CHW
                                 + (size_t)(d0 + (dg << 3)) * HWSZ + hw0 + n;
                float f[8];
                #pragma unroll
                for (int j = 0; j < 8; ++j) f[j] = src[(size_t)j * HWSZ];
                short8v hv, lv;
                #pragma unroll
                for (int j = 0; j < 8; ++j) {
                    unsigned short hb = bf16_rne(f[j]);
                    unsigned short lb = bf16_rne(f[j] - bf16_tf(hb));
                    hv[j] = (short)hb; lv[j] = (short)lb;
                }
                int base = ((n >> 4) << 10) + ((dg >> 2) << 9)
                         + (((n & 15) + ((dg & 3) << 4)) << 3);
                *(short8v*)&ZH[base] = hv;
                *(short8v*)&ZL[base] = lv;
            }
            for (int dc = 0; dc < 2; ++dc) {
                const int s32 = (dh << 1) + dc;
                if (dc) __syncthreads();     // E(dc=0) readers done
                #pragma unroll
                for (int p = 0; p < 4; ++p) {   // stage E 32-d chunk: 2048 uint4
                    int s = p * 512 + t;
                    int arr = s >> 10, ss = s & 1023;
                    int kwl = ss >> 6, ww = ss & 63;
                    const uint4* src = (arr ? el4 : eh4)
                        + (size_t)(((kt << 4) + kwl) << 9) + (s32 << 6) + ww;
                    (arr ? ((uint4*)EL) : ((uint4*)EH))[ss] = *src;
                }
                __syncthreads();
                short8v ah[4], al[4], bh[4], bl[4];
                #pragma unroll
                for (int kf = 0; kf < 4; ++kf) {
                    int base = ((kwv * 4 + kf) << 9) + l8;
                    ah[kf] = *(const short8v*)&EH[base];
                    al[kf] = *(const short8v*)&EL[base];
                }
                #pragma unroll
                for (int nf = 0; nf < 4; ++nf) {
                    int base = ((nwv * 4 + nf) << 10) + (dc << 9) + l8;
                    bh[nf] = *(const short8v*)&ZH[base];
                    bl[nf] = *(const short8v*)&ZL[base];
                }
                #pragma unroll
                for (int kf = 0; kf < 4; ++kf)
                    #pragma unroll
                    for (int nf = 0; nf < 4; ++nf) {
                        acc[kf][nf] = __builtin_amdgcn_mfma_f32_16x16x32_bf16(ah[kf], bh[nf], acc[kf][nf], 0, 0, 0);
                        acc[kf][nf] = __builtin_amdgcn_mfma_f32_16x16x32_bf16(ah[kf], bl[nf], acc[kf][nf], 0, 0, 0);
                        acc[kf][nf] = __builtin_amdgcn_mfma_f32_16x16x32_bf16(al[kf], bh[nf], acc[kf][nf], 0, 0, 0);
                    }
            }
        }
        // fold into running top-2 (ref-bucketed score, first-index ties)
        #pragma unroll
        for (int kf = 0; kf < 4; ++kf)
            #pragma unroll
            for (int nf = 0; nf < 4; ++nf)
                #pragma unroll
                for (int r = 0; r < 4; ++r) {
                    int k = kt * 256 + kwv * 64 + kf * 16 + g2 * 4 + r;
                    float s = __fsub_rn(__fadd_rn(an[nf], BNs[k]),
                                        __fmul_rn(2.0f, acc[kf][nf][r]));
                    if (s < mv1[nf] || (s == mv1[nf] && k < mi1[nf])) {
                        mv2[nf] = fminf(mv2[nf], mv1[nf]);
                        mv1[nf] = s; mi1[nf] = k;
                    } else if (s < mv2[nf]) mv2[nf] = s;
                }
    }

    __syncthreads();   // E no longer needed -> alias EBUF as RED / FIDX
    float* REDv = (float*)EBUF4;
    int*   REDi = (int*)((char*)EBUF4 + 8192);
    float* REDw = (float*)((char*)EBUF4 + 16384);
    int*   FIDX = (int*)((char*)EBUF4 + 24576);

    #pragma unroll
    for (int nf = 0; nf < 4; ++nf) {
        int nl = nf * 16 + (lane & 15);
        int slot = kwv * 4 + g2;
        REDv[(nwv * 64 + nl) * 16 + slot] = mv1[nf];
        REDi[(nwv * 64 + nl) * 16 + slot] = mi1[nf];
        REDw[(nwv * 64 + nl) * 16 + slot] = mv2[nf];
    }
    __syncthreads();
    if (t < 128) {
        float bv = 3.4e38f, b2 = 3.4e38f; int bi = 0x7fffffff;
        #pragma unroll
        for (int s = 0; s < 16; ++s) {
            float v1 = REDv[t * 16 + s];
            float v2 = REDw[t * 16 + s];
            int   i1 = REDi[t * 16 + s];
            if (v1 < bv || (v1 == bv && i1 < bi)) { b2 = fminf(b2, bv); bv = v1; bi = i1; }
            else b2 = fminf(b2, v1);
            b2 = fminf(b2, v2);
        }
        int n_glob = nb * 128 + t;
        idx_out[n_glob] = (float)bi;
        FIDX[t] = bi;
        if (b2 - bv < TAU_GAP) {
            int pos = atomicAdd(cnt, 1);
            list[pos] = n_glob;
        }
        float lsum = bv;
        #pragma unroll
        for (int off = 32; off > 0; off >>= 1)
            lsum += __shfl_down(lsum, off, 64);
        if ((t & 63) == 0) atomicAdd(loss_slot, lsum * (1.25f / 16777216.f));
    }
    if (WRITE_OUT) {
        __syncthreads();
        int n_loc = t & 127, cg = t >> 7;    // cg: 4 groups of 64 channels
        int idx = FIDX[n_loc];
        int hw = hw0 + n_loc;
        const float4* erow = (const float4*)(emb + (size_t)idx * DDIM + (cg << 6));
        float* obase = outp + (size_t)b * CHW + (size_t)(cg << 6) * HWSZ + hw;
        #pragma unroll 4
        for (int q = 0; q < 16; ++q) {
            float4 v = erow[q];
            obase[(size_t)(q * 4 + 0) * HWSZ] = v.x;
            obase[(size_t)(q * 4 + 1) * HWSZ] = v.y;
            obase[(size_t)(q * 4 + 2) * HWSZ] = v.z;
            obase[(size_t)(q * 4 + 3) * HWSZ] = v.w;
        }
    }
}

// ---- exact (f64-dot) rescore of near-tied rows (+ out-row patch) ----------
template<bool WRITE_OUT>
__global__ __launch_bounds__(256) void vq_rescore(const float* __restrict__ z,
                                                  const float* __restrict__ emb,
                                                  const float* __restrict__ An,
                                                  const float* __restrict__ Bn,
                                                  float* __restrict__ idx_out,
                                                  const int* __restrict__ list,
                                                  const int* __restrict__ cnt,
                                                  float* __restrict__ outp) {
    const int c = *cnt;
    const int t = threadIdx.x;
    __shared__ float zs[256];
    __shared__ float sv[256];
    __shared__ int   si[256];
    for (int i = blockIdx.x; i < c; i += gridDim.x) {
        int n = list[i];
        int b = n >> 10, hw = n & 1023;
        __syncthreads();
        zs[t] = z[(size_t)b * CHW + (size_t)t * HWSZ + hw];
        __syncthreads();
        float Anv = An[n];
        float bestv = 3.4e38f; int besti = 0x7fffffff;
        #pragma unroll
        for (int kb = 0; kb < 4; ++kb) {
            int k = kb * 256 + t;
            const float4* e4 = (const float4*)(emb + (size_t)k * DDIM);
            double dot = 0.0;
            for (int q = 0; q < 64; ++q) {
                float4 v = e4[q];
                const float* zq = &zs[q << 2];
                dot += (double)v.x * zq[0] + (double)v.y * zq[1]
                     + (double)v.z * zq[2] + (double)v.w * zq[3];
            }
            float s = __fsub_rn(__fadd_rn(Anv, Bn[k]),
                                __fmul_rn(2.0f, (float)dot));
            if (s < bestv || (s == bestv && k < besti)) { bestv = s; besti = k; }
        }
        sv[t] = bestv; si[t] = besti;
        __syncthreads();
        for (int st = 128; st > 0; st >>= 1) {
            if (t < st) {
                float ov = sv[t + st]; int oi = si[t + st];
                if (ov < sv[t] || (ov == sv[t] && oi < si[t])) { sv[t] = ov; si[t] = oi; }
            }
            __syncthreads();
        }
        if (t == 0) idx_out[n] = (float)si[0];
        if (WRITE_OUT) {
            int widx = si[0];
            outp[(size_t)b * CHW + (size_t)t * HWSZ + hw] =
                emb[(size_t)widx * DDIM + t];
        }
    }
}

// ---- path B epilogue: gather codebook rows -> out -------------------------
__global__ __launch_bounds__(256) void vq_epilogue(const float* __restrict__ emb,
                                                   float* __restrict__ outp,
                                                   const float* __restrict__ idxf) {
    const int t  = threadIdx.x;
    const int nc = blockIdx.x;
    const int b  = nc >> 4;
    const int hw = ((nc & 15) << 6) + (t & 63);
    const int n  = (b << 10) + hw;
    const int idx = (int)idxf[n];
    const float* erow = emb + (size_t)idx * DDIM;
    const size_t zb = (size_t)b * CHW + hw;

    const int cbase = (t >> 6) << 2;
    #pragma unroll 4
    for (int cq = 0; cq < 16; ++cq) {
        int c = cbase + (cq << 4);
        float4 q4 = *reinterpret_cast<const float4*>(erow + c);
        outp[zb + (size_t)(c + 0) * HWSZ] = q4.x;
        outp[zb + (size_t)(c + 1) * HWSZ] = q4.y;
        outp[zb + (size_t)(c + 2) * HWSZ] = q4.z;
        outp[zb + (size_t)(c + 3) * HWSZ] = q4.w;
    }
}

extern "C" void kernel_launch(void* const* d_in, const int* in_sizes, int n_in,
                              void* d_out, int out_size, void* d_ws, size_t ws_size,
                              hipStream_t stream) {
    const float* z   = (const float*)d_in[0];
    const float* emb = (const float*)d_in[1];
    float* out       = (float*)d_out;
    float* loss_slot = out + LOSS_OFF;
    float* idx_out   = out + IDX_OFF;

    if (ws_size >= (size_t)WS_NEED) {
        // path A: scratch in ws; out-write fused into argmin + rescore
        char* ws = (char*)d_ws;
        unsigned short* EHg = (unsigned short*)(ws + WS_EH);
        unsigned short* ELg = (unsigned short*)(ws + WS_EL);
        float* An = (float*)(ws + WS_AN);
        float* Bn = (float*)(ws + WS_BN);
        int*  list = (int*)(ws + WS_LIST);
        int*  cnt  = (int*)(ws + WS_CNT);

        vq_prep_bn         <<<dim3(16),  dim3(64),  0, stream>>>(emb, Bn, loss_slot, cnt);
        vq_prep_scatter    <<<dim3(128), dim3(256), 0, stream>>>(emb, EHg, ELg);
        vq_znorm           <<<dim3(256), dim3(256), 0, stream>>>(z, An);
        vq_argmin_conv<true><<<dim3(512), dim3(512), 0, stream>>>(z, EHg, ELg, An, Bn,
                                idx_out, list, cnt, loss_slot, out, emb);
        vq_rescore<true>   <<<dim3(512), dim3(256), 0, stream>>>(z, emb, An, Bn,
                                idx_out, list, cnt, out);
    } else {
        // path B: scratch carved from the out region (r5/r6-proven layout);
        // no fused out-write (it would clobber scratch) -> separate epilogue.
        unsigned short* EHg = (unsigned short*)(out + EH_OFF);
        unsigned short* ELg = (unsigned short*)(out + EL_OFF);
        float* An = out + AN_OFF;
        float* Bn = out + BN_OFF;
        int*  list = (int*)(out + LIST_OFF);
        int*  cnt  = (int*)(out + CNT_OFF);

        vq_prep_bn          <<<dim3(16),  dim3(64),  0, stream>>>(emb, Bn, loss_slot, cnt);
        vq_prep_scatter     <<<dim3(128), dim3(256), 0, stream>>>(emb, EHg, ELg);
        vq_znorm            <<<dim3(256), dim3(256), 0, stream>>>(z, An);
        vq_argmin_conv<false><<<dim3(512), dim3(512), 0, stream>>>(z, EHg, ELg, An, Bn,
                                 idx_out, list, cnt, loss_slot, out, emb);
        vq_rescore<false>   <<<dim3(512), dim3(256), 0, stream>>>(z, emb, An, Bn,
                                 idx_out, list, cnt, out);
        vq_epilogue         <<<dim3(1024), dim3(256), 0, stream>>>(emb, out, idx_out);
    }
}